// Round 3
// baseline (387.976 us; speedup 1.0000x reference)
//
#include <hip/hip_runtime.h>

// KL(N(mu_p, diag(exp(ls_p))) || N(mu_q, diag(exp(ls_q)))), closed form,
// reduced to a single scalar:
//   out = 0.5 * ( S / N_samples - d )
// where S = sum over ALL elements of
//   elem = r + exp(-r) + (m_q - m_p)^2 * exp(-ls_q),  r = ls_q - ls_p
// Shapes: (2, 3, 160, 192, 160) fp32. N_total = 29,491,200. n4 = 7,372,800.
//
// Pure-read memory-bound: 472 MB, pinned at 3.3 TB/s delivered across three
// different schedules (VGPR 16/36/28 — compiler re-serialized every attempt
// at deep load batching). This version FORCES a 12-deep load batch:
// explicit load block -> __builtin_amdgcn_sched_barrier(0) -> compute block.
// The fence stops the scheduler from interleaving compute into the loads,
// so all 12 float4 results must be live simultaneously (VGPR >= ~56 is the
// proof it happened). Per-wave contiguous strips: lane l reads quads at
// wavebase + l + {0,64,128} -> byte offsets {0,1024,2048}, foldable into
// global_load immediate offsets, one shared voffset. launch_bounds(256,6)
// keeps >=6 waves/SIMD. If this STILL lands at 142 us, the per-CU
// outstanding-read cap (~3.3 TB/s read direction, = m13 copy's read side)
// is confirmed by elimination -> roofline.

#define BLOCKS   2048
#define THREADS  256
#define NWAVES   (THREADS / 64)

__device__ __forceinline__ float kl4(float4 a, float4 b, float4 c, float4 d)
{
    float dx = c.x - a.x, dy = c.y - a.y, dz = c.z - a.z, dw = c.w - a.w;
    float rx = d.x - b.x, ry = d.y - b.y, rz = d.z - b.z, rw = d.w - b.w;
    float e0 = rx + __expf(-rx) + dx * dx * __expf(-d.x);
    float e1 = ry + __expf(-ry) + dy * dy * __expf(-d.y);
    float e2 = rz + __expf(-rz) + dz * dz * __expf(-d.z);
    float e3 = rw + __expf(-rw) + dw * dw * __expf(-d.w);
    return (e0 + e1) + (e2 + e3);
}

__global__ __launch_bounds__(THREADS, 6) void kl_reduce_kernel(
    const float4* __restrict__ mp, const float4* __restrict__ lsp,
    const float4* __restrict__ mq, const float4* __restrict__ lsq,
    double* __restrict__ partials, long n4)
{
    // Balanced contiguous split across blocks (rem = 0 for this shape),
    // then split each block's span into 4 contiguous per-wave strips.
    const long per    = n4 / BLOCKS;
    const long rem    = n4 % BLOCKS;
    const long b      = blockIdx.x;
    const long bstart = b * per + (b < rem ? b : rem);
    const long bend   = bstart + per + (b < rem ? 1 : 0);

    const int wave = threadIdx.x >> 6;
    const int lane = threadIdx.x & 63;

    const long bn     = bend - bstart;
    const long wper   = bn / NWAVES;
    const long wstart = bstart + (long)wave * wper;
    const long wend   = (wave == NWAVES - 1) ? bend : (wstart + wper);

    double acc = 0.0;
    long i = wstart + lane;

    // Uniform trip count: 3 quads x 64 lanes = 192 float4 per wave-iter.
    const long nfull = (wend - wstart) / 192;
    for (long k = 0; k < nfull; ++k, i += 192) {
        // ---- load block: 12 x global_load_dwordx4, all issued before any
        // compute (sched_barrier(0) below forbids crossing) ----
        float4 a0 = mp [i], a1 = mp [i + 64], a2 = mp [i + 128];
        float4 b0 = lsp[i], b1 = lsp[i + 64], b2 = lsp[i + 128];
        float4 c0 = mq [i], c1 = mq [i + 64], c2 = mq [i + 128];
        float4 d0 = lsq[i], d1 = lsq[i + 64], d2 = lsq[i + 128];
        __builtin_amdgcn_sched_barrier(0);
        // ---- compute block ----
        acc += (double)kl4(a0, b0, c0, d0);
        acc += (double)kl4(a1, b1, c1, d1);
        acc += (double)kl4(a2, b2, c2, d2);
    }
    // Tail: remaining quads of this wave's strip (~2 rounds).
    for (; i < wend; i += 64)
        acc += (double)kl4(mp[i], lsp[i], mq[i], lsq[i]);

    // wave (64-lane) reduction
#pragma unroll
    for (int off = 32; off > 0; off >>= 1)
        acc += __shfl_down(acc, off, 64);

    __shared__ double sdata[NWAVES];
    if (lane == 0) sdata[wave] = acc;
    __syncthreads();

    if (threadIdx.x == 0) {
        double s = 0.0;
#pragma unroll
        for (int w = 0; w < NWAVES; ++w) s += sdata[w];
        partials[blockIdx.x] = s;
    }
}

__global__ __launch_bounds__(256) void kl_finalize_kernel(
    const double* __restrict__ partials, int nblocks,
    float* __restrict__ out, double inv_nsamp, double dch)
{
    double acc = 0.0;
    for (int i = threadIdx.x; i < nblocks; i += blockDim.x)
        acc += partials[i];

#pragma unroll
    for (int off = 32; off > 0; off >>= 1)
        acc += __shfl_down(acc, off, 64);

    __shared__ double sdata[4];
    int wave = threadIdx.x >> 6;
    if ((threadIdx.x & 63) == 0) sdata[wave] = acc;
    __syncthreads();

    if (threadIdx.x == 0) {
        double s = 0.0;
#pragma unroll
        for (int w = 0; w < 4; ++w) s += sdata[w];
        out[0] = (float)(0.5 * (s * inv_nsamp - dch));
    }
}

extern "C" void kernel_launch(void* const* d_in, const int* in_sizes, int n_in,
                              void* d_out, int out_size, void* d_ws, size_t ws_size,
                              hipStream_t stream) {
    const float4* mp  = (const float4*)d_in[0];
    const float4* lsp = (const float4*)d_in[1];
    const float4* mq  = (const float4*)d_in[2];
    const float4* lsq = (const float4*)d_in[3];

    long n_total = (long)in_sizes[0];       // 29,491,200
    long n4 = n_total / 4;                  // exactly divisible
    const long d_ch = 3;
    double n_samples = (double)(n_total / d_ch);

    double* partials = (double*)d_ws;       // BLOCKS * 8 bytes = 16 KB

    kl_reduce_kernel<<<BLOCKS, THREADS, 0, stream>>>(mp, lsp, mq, lsq, partials, n4);
    kl_finalize_kernel<<<1, 256, 0, stream>>>(partials, BLOCKS, (float*)d_out,
                                              1.0 / n_samples, (double)d_ch);
}